// Round 7
// baseline (176.409 us; speedup 1.0000x reference)
//
#include <hip/hip_runtime.h>
#include <math.h>

typedef __attribute__((ext_vector_type(8))) short short8v;
typedef __attribute__((ext_vector_type(4))) float f32x4;

static constexpr float RCf = 5.0f;
static constexpr float PIf = 3.14159265358979323846f;

__device__ inline unsigned short f2bf(float f) {
    union { float f; unsigned u; } x; x.f = f;
    unsigned u = x.u;
    unsigned r = (u + 0x7fffu + ((u >> 16) & 1u)) >> 16;
    return (unsigned short)r;
}

// ---------------------------------------------------------------------------
// CSR build: count -> scan -> fill
// ---------------------------------------------------------------------------
__global__ __launch_bounds__(256) void count_kernel(
    const int* __restrict__ pairs, int* __restrict__ cnt, int n_pairs)
{
    int p = blockIdx.x * 256 + threadIdx.x;
    if (p < n_pairs) atomicAdd(&cnt[pairs[2 * p]], 1);
}

__global__ __launch_bounds__(256) void scan_kernel(
    const int* __restrict__ cnt, int* __restrict__ off, int n_atoms)
{
    __shared__ int part[256];
    int t = threadIdx.x;
    const int per = 16;
    int base = t * per;
    int local[16];
    int s = 0;
#pragma unroll
    for (int k = 0; k < per; k++) {
        int v = (base + k < n_atoms) ? cnt[base + k] : 0;
        local[k] = s;
        s += v;
    }
    part[t] = s;
    __syncthreads();
    for (int d = 1; d < 256; d <<= 1) {
        int v = (t >= d) ? part[t - d] : 0;
        __syncthreads();
        part[t] += v;
        __syncthreads();
    }
    int pre = (t == 0) ? 0 : part[t - 1];
#pragma unroll
    for (int k = 0; k < per; k++)
        if (base + k < n_atoms) off[base + k] = pre + local[k];
}

__global__ __launch_bounds__(256) void fill_kernel(
    const int* __restrict__ pairs, const int* __restrict__ off,
    int* __restrict__ cursor, int* __restrict__ idx, int n_pairs)
{
    int p = blockIdx.x * 256 + threadIdx.x;
    if (p >= n_pairs) return;
    int i = pairs[2 * p];
    int slot = atomicAdd(&cursor[i], 1);
    idx[off[i] + slot] = p;
}

// ---------------------------------------------------------------------------
// Transpose + bf16 cast: W [q][K][N] f32 -> WT [(q*N + n)][K] bf16  (for W2)
// ---------------------------------------------------------------------------
__global__ __launch_bounds__(256) void transpose_w(
    const float* __restrict__ W, unsigned short* __restrict__ WT, int K, int N)
{
    __shared__ float tile[64][65];
    int q = blockIdx.z;
    int k0 = blockIdx.x * 64, n0 = blockIdx.y * 64;
    const float* Wq = W + (size_t)q * K * N;
    int t = threadIdx.x;
    int kl = t >> 6, nl = t & 63;
#pragma unroll
    for (int i = 0; i < 16; i++)
        tile[kl + i * 4][nl] = Wq[(size_t)(k0 + kl + i * 4) * N + n0 + nl];
    __syncthreads();
    int nr = t >> 2, kc = (t & 3) * 16;
    unsigned short* dst = WT + ((size_t)q * N + n0 + nr) * K + k0 + kc;
    short8v v0, v1;
#pragma unroll
    for (int i = 0; i < 8; i++) {
        v0[i] = (short)f2bf(tile[kc + i][nr]);
        v1[i] = (short)f2bf(tile[kc + 8 + i][nr]);
    }
    *(short8v*)(dst) = v0;
    *(short8v*)(dst + 8) = v1;
}

// ---------------------------------------------------------------------------
// Symmetry-folded W1 prep:
//   W1symT[(q*256+h)][u] = gamma[p1]*W1[q][p1][h] + (p1!=p2)*gamma[p2]*W1[q][p2][h]
//   b1[q][h]            = sum_pos beta[pos]*W1[q][pos][h]
// u enumerates (l, A<=B), A=(a*8+n), B=(b*8+k), pos = l*1024+a*256+b*64+n*8+k.
// grid (33, 4): 64 u's per block; thread = h; register-buffered short8v stores.
// ---------------------------------------------------------------------------
__global__ __launch_bounds__(256) void prep_w1sym(
    const float* __restrict__ W1, const float* __restrict__ gamma,
    const float* __restrict__ beta, unsigned short* __restrict__ W1symT,
    float* __restrict__ b1)
{
    int u0 = blockIdx.x * 64;
    int q = blockIdx.y;
    int h = threadIdx.x;
    int l = u0 / 528, r = u0 % 528;
    int A = 0;
    while ((A + 1) * 32 - (A + 1) * A / 2 <= r) A++;     // rowstart(A+1) <= r
    int B = A + (r - (A * 32 - A * (A - 1) / 2));

    const float* W1q = W1 + (size_t)q * 4096 * 256;
    unsigned short* dst = W1symT + ((size_t)q * 256 + h) * 2112 + u0;
    float bacc = 0.0f;
    short8v buf;
#pragma unroll 1
    for (int uu = 0; uu < 64; uu++) {
        int pos1 = l * 1024 + (A >> 3) * 256 + (B >> 3) * 64 + (A & 7) * 8 + (B & 7);
        float w1 = W1q[(size_t)pos1 * 256 + h];
        float v = gamma[pos1] * w1;
        bacc += beta[pos1] * w1;
        if (A < B) {
            int pos2 = l * 1024 + (B >> 3) * 256 + (A >> 3) * 64 + (B & 7) * 8 + (A & 7);
            float w2 = W1q[(size_t)pos2 * 256 + h];
            v += gamma[pos2] * w2;
            bacc += beta[pos2] * w2;
        }
        buf[uu & 7] = (short)f2bf(v);
        if ((uu & 7) == 7)
            *(short8v*)(dst + (uu & ~7)) = buf;
        B++;
        if (B == 32) { A++; B = A; if (A == 32) { A = 0; B = 0; l++; } }
    }
    atomicAdd(&b1[q * 256 + h], bacc);
}

// ---------------------------------------------------------------------------
// Fused gather + power-spectrum + LayerNorm -> unique-position bf16 Fu.
// Fu[atom][u] = (f_u - mean)*rs for A<=B (2112 values); gamma/beta folded
// into W1sym/b1. One block (256 threads) per atom.
// ---------------------------------------------------------------------------
__global__ __launch_bounds__(256) void gather_atom_kernel(
    const float* __restrict__ pos, const int* __restrict__ pairs,
    const int* __restrict__ species, const float* __restrict__ W_rad,
    const float* __restrict__ W_alch, const int* __restrict__ off,
    const int* __restrict__ idx, unsigned short* __restrict__ Fu,
    int n_atoms, int n_pairs)
{
    int atom = blockIdx.x;
    int t = threadIdx.x;
    __shared__ float wr2[512];        // W_rad transposed: [rr][n*4+l]
    __shared__ float raw_sh[16][16];
    __shared__ float Y_sh[16][16];
    __shared__ float wal_sh[16][4];
    __shared__ float R_sh[16][32];    // [pair][n*4+l]
    __shared__ float part[2][512];
    __shared__ float c_sh[512];
    __shared__ float red[8];

    for (int u = t; u < 512; u += 256) {
        int l = u >> 7, rr = (u >> 3) & 15, n = u & 7;
        wr2[rr * 32 + n * 4 + l] = W_rad[u];
    }

    int p0 = off[atom];
    int p1 = (atom + 1 < n_atoms) ? off[atom + 1] : n_pairs;
    int npair = p1 - p0;

    float px = pos[3 * atom], py = pos[3 * atom + 1], pz = pos[3 * atom + 2];

    int half = t >> 7, e = t & 127;
    int lm = e >> 3, nn = e & 7;
    int l_of = (lm > 0) + (lm > 3) + (lm > 8);
    int nl_of = nn * 4 + l_of;
    float acc0 = 0.f, acc1 = 0.f, acc2 = 0.f, acc3 = 0.f;

    __syncthreads();

    for (int done = 0; done < npair; done += 16) {
        int pp = t >> 4, sub = t & 15;
        // ---- A1: geometry + raw + Y + walch for 16 pairs ----
        {
            int k = done + pp;
            float xx = 0.f, yy = 0.f, zz = 0.f;
            int sj = 0;
            if (k < npair) {
                int pid = idx[p0 + k];
                int j = pairs[2 * pid + 1];
                sj = species[j];
                float dx = pos[3 * j]     - px;
                float dy = pos[3 * j + 1] - py;
                float dz = pos[3 * j + 2] - pz;
                float r = sqrtf(dx * dx + dy * dy + dz * dz + 1e-12f);
                float inv = 1.0f / r;
                xx = dx * inv; yy = dy * inv; zz = dz * inv;
                float fc = (r < RCf) ? 0.5f * (cosf((PIf / RCf) * r) + 1.0f) : 0.0f;
                float mu = (RCf / 15.0f) * (float)sub;
                float tt = (r - mu) * (16.0f / RCf);
                raw_sh[pp][sub] = expf(-tt * tt) * fc;
            } else {
                raw_sh[pp][sub] = 0.0f;
            }
            float x2 = xx * xx, y2 = yy * yy, z2 = zz * zz;
            float yv;
            switch (sub) {
                case 0:  yv = 0.28209479177387814f; break;
                case 1:  yv = 0.4886025119029199f * yy; break;
                case 2:  yv = 0.4886025119029199f * zz; break;
                case 3:  yv = 0.4886025119029199f * xx; break;
                case 4:  yv = 1.0925484305920792f * xx * yy; break;
                case 5:  yv = 1.0925484305920792f * yy * zz; break;
                case 6:  yv = 0.31539156525252005f * (3.0f * z2 - 1.0f); break;
                case 7:  yv = 1.0925484305920792f * xx * zz; break;
                case 8:  yv = 0.5462742152960396f * (x2 - y2); break;
                case 9:  yv = 0.5900435899266435f * yy * (3.0f * x2 - y2); break;
                case 10: yv = 2.890611442640554f * xx * yy * zz; break;
                case 11: yv = 0.4570457994644658f * yy * (5.0f * z2 - 1.0f); break;
                case 12: yv = 0.3731763325901154f * zz * (5.0f * z2 - 3.0f); break;
                case 13: yv = 0.4570457994644658f * xx * (5.0f * z2 - 1.0f); break;
                case 14: yv = 1.445305721320277f * zz * (x2 - y2); break;
                default: yv = 0.5900435899266435f * xx * (x2 - 3.0f * y2); break;
            }
            Y_sh[pp][sub] = yv;
            if (sub < 4) wal_sh[pp][sub] = W_alch[sj * 4 + sub];
        }
        __syncthreads();
        // ---- A1.5: R_sh[pp][n*4+l] ----
#pragma unroll
        for (int rep = 0; rep < 2; rep++) {
            int id = rep * 256 + t;
            int pp2 = id >> 5, nl = id & 31;
            float acc = 0.f;
            const float* rw = raw_sh[pp2];
            const float* wv = &wr2[nl];
#pragma unroll
            for (int rr = 0; rr < 16; rr++)
                acc = fmaf(rw[rr], wv[rr * 32], acc);
            R_sh[pp2][nl] = acc;
        }
        __syncthreads();
        // ---- A2: accumulate 8 pairs per half ----
        int base = half * 8;
#pragma unroll
        for (int pq = 0; pq < 8; pq++) {
            int pp2 = base + pq;
            float contrib = Y_sh[pp2][lm] * R_sh[pp2][nl_of];
            const float* wa = wal_sh[pp2];
            acc0 = fmaf(wa[0], contrib, acc0);
            acc1 = fmaf(wa[1], contrib, acc1);
            acc2 = fmaf(wa[2], contrib, acc2);
            acc3 = fmaf(wa[3], contrib, acc3);
        }
        __syncthreads();
    }

    part[half][0 * 128 + e] = acc0;
    part[half][1 * 128 + e] = acc1;
    part[half][2 * 128 + e] = acc2;
    part[half][3 * 128 + e] = acc3;
    __syncthreads();
    c_sh[t]       = part[0][t]       + part[1][t];
    c_sh[t + 256] = part[0][t + 256] + part[1][t + 256];
    __syncthreads();

    const float invsq[4] = {1.0f, 0.57735026918962576f, 0.44721359549995794f,
                            0.37796447300922722f};
    int b = t >> 6, n = (t >> 3) & 7, k = t & 7;
    float fv[16];
    float lsum = 0.0f;
#pragma unroll
    for (int ii = 0; ii < 16; ii++) {
        int l = ii >> 2, a = ii & 3;
        int base = l * l;
        float acc = 0.0f;
        int cntm = 2 * l + 1;
        for (int m = 0; m < cntm; m++)
            acc = fmaf(c_sh[a * 128 + (base + m) * 8 + n],
                       c_sh[b * 128 + (base + m) * 8 + k], acc);
        acc *= invsq[l];
        fv[ii] = acc;
        lsum += acc;
    }

    float v = lsum;
#pragma unroll
    for (int o = 1; o < 64; o <<= 1) v += __shfl_xor(v, o, 64);
    int wid = t >> 6, lane = t & 63;
    if (lane == 0) red[wid] = v;
    __syncthreads();
    float mean = (red[0] + red[1] + red[2] + red[3]) * (1.0f / 4096.0f);

    float lss = 0.0f;
#pragma unroll
    for (int ii = 0; ii < 16; ii++) {
        float d = fv[ii] - mean;
        lss += d * d;
    }
    v = lss;
#pragma unroll
    for (int o = 1; o < 64; o <<= 1) v += __shfl_xor(v, o, 64);
    if (lane == 0) red[4 + wid] = v;
    __syncthreads();
    float var = (red[4] + red[5] + red[6] + red[7]) * (1.0f / 4096.0f);
    float rs = rsqrtf(var + 1e-5f);

    // write only unique positions A<=B:  u = l*528 + 32A - A(A+1)/2 + B
    unsigned short* Fo = Fu + (size_t)atom * 2112;
    int B = b * 8 + k;
#pragma unroll
    for (int ii = 0; ii < 16; ii++) {
        int l = ii >> 2, a = ii & 3;
        int A = a * 8 + n;
        if (A <= B) {
            int u = l * 528 + A * 32 - (A * (A + 1)) / 2 + B;
            Fo[u] = f2bf((fv[ii] - mean) * rs);
        }
    }
}

// ---------------------------------------------------------------------------
// bf16 MFMA GEMM, SINGLE-buffer (24 KB LDS). Measured: single-buffer 66-69 µs
// vs dbuf-48KB 81 µs (occupancy loss beats overlap — keep single).
// NO XCD swizzle (round-4: tripled FETCH; default dispatch already co-locates
// A-tile sharers). BM=128, BN=64, BK=64; chunk-XOR LDS swizzle (rule #21).
//   MODE 1: A=Fu K=2112; v=(acc+b1[q,h])*alch; silu -> bf16 H1 (all rows).
//   MODE 2: per-q K=256; fused W_last dot -> atomicAdd e[row].
// ---------------------------------------------------------------------------
template<int MODE>
__global__ __launch_bounds__(256) void gemm_mfma(
    const unsigned short* __restrict__ A, const unsigned short* __restrict__ B,
    void* __restrict__ C, int M, int K, long sAq, long sBq,
    const int* __restrict__ species, const float* __restrict__ W_alch,
    const float* __restrict__ W_last, const float* __restrict__ b1)
{
    __shared__ unsigned short As[128 * 64];  // 16 KB
    __shared__ unsigned short Bs[64 * 64];   // 8 KB
    int t = threadIdx.x, w = t >> 6, lane = t & 63;
    int bm = blockIdx.x * 128, bn = blockIdx.y * 64;
    int q = blockIdx.z;

    const unsigned short* Aq = A + (size_t)q * sAq;
    const unsigned short* Bq = B + (size_t)q * sBq;
    int ldab = K * 2;

    long srcoff = (long)(lane >> 3) * ldab + (long)(((lane & 7) ^ (lane >> 3)) << 4);
    const char* Ab = (const char*)Aq + (size_t)bm * ldab + srcoff;
    const char* Bb = (const char*)Bq + (size_t)bn * ldab + srcoff;

    int wr = w >> 1, wc = w & 1;
    f32x4 acc[4][2];
#pragma unroll
    for (int i = 0; i < 4; i++)
#pragma unroll
        for (int j = 0; j < 2; j++) acc[i][j] = (f32x4){0.f, 0.f, 0.f, 0.f};

    int l15 = lane & 15, l16 = lane >> 4;
    int rA0 = wr * 64 + l15;
    int rB0 = wc * 32 + l15;
    int cb0 = l16 * 16;
    int swzA = (rA0 & 7) << 4, swzB = (rB0 & 7) << 4;

    for (int k0 = 0; k0 < K; k0 += 64) {
        long kb = (long)k0 * 2;
#pragma unroll
        for (int i = 0; i < 4; i++) {
            int c = w * 4 + i;
            __builtin_amdgcn_global_load_lds(
                (const __attribute__((address_space(1))) unsigned int*)(Ab + (size_t)(c * 8) * ldab + kb),
                (__attribute__((address_space(3))) unsigned int*)(As + c * 512), 16, 0, 0);
        }
#pragma unroll
        for (int i = 0; i < 2; i++) {
            int c = w * 2 + i;
            __builtin_amdgcn_global_load_lds(
                (const __attribute__((address_space(1))) unsigned int*)(Bb + (size_t)(c * 8) * ldab + kb),
                (__attribute__((address_space(3))) unsigned int*)(Bs + c * 512), 16, 0, 0);
        }
        __syncthreads();

        short8v a[4][2], bfr[2][2];
#pragma unroll
        for (int mb = 0; mb < 4; mb++)
#pragma unroll
            for (int kk = 0; kk < 2; kk++) {
                int addr = (rA0 + mb * 16) * 128 + ((cb0 + kk * 64) ^ swzA);
                a[mb][kk] = *(const short8v*)((const char*)As + addr);
            }
#pragma unroll
        for (int nb = 0; nb < 2; nb++)
#pragma unroll
            for (int kk = 0; kk < 2; kk++) {
                int addr = (rB0 + nb * 16) * 128 + ((cb0 + kk * 64) ^ swzB);
                bfr[nb][kk] = *(const short8v*)((const char*)Bs + addr);
            }
#pragma unroll
        for (int kk = 0; kk < 2; kk++)
#pragma unroll
            for (int mb = 0; mb < 4; mb++)
#pragma unroll
                for (int nb = 0; nb < 2; nb++)
                    acc[mb][nb] = __builtin_amdgcn_mfma_f32_16x16x32_bf16(
                        a[mb][kk], bfr[nb][kk], acc[mb][nb], 0, 0, 0);
        __syncthreads();
    }

    int colbase = bn + wc * 32 + l15;
    if (MODE == 1) {
#pragma unroll
        for (int mb = 0; mb < 4; mb++) {
#pragma unroll
            for (int j = 0; j < 4; j++) {
                int row = bm + wr * 64 + mb * 16 + l16 * 4 + j;
                int sp = species[row < M ? row : (M - 1)];
#pragma unroll
                for (int nb = 0; nb < 2; nb++) {
                    int gcol = colbase + nb * 16;
                    int qq = gcol >> 8, hc = gcol & 255;
                    float v = (acc[mb][nb][j] + b1[gcol]) * W_alch[sp * 4 + qq];
                    v = v / (1.0f + expf(-v));
                    ((unsigned short*)C)[((size_t)qq * 4096 + row) * 256 + hc] = f2bf(v);
                }
            }
        }
    } else {
        float wl0 = W_last[q * 256 + colbase];
        float wl1 = W_last[q * 256 + colbase + 16];
        float* e = (float*)C;
#pragma unroll
        for (int mb = 0; mb < 4; mb++) {
#pragma unroll
            for (int j = 0; j < 4; j++) {
                int row = bm + wr * 64 + mb * 16 + l16 * 4 + j;
                float v0 = acc[mb][0][j]; v0 = v0 / (1.0f + expf(-v0));
                float v1 = acc[mb][1][j]; v1 = v1 / (1.0f + expf(-v1));
                float part = v0 * wl0 + v1 * wl1;
                part += __shfl_xor(part, 1, 64);
                part += __shfl_xor(part, 2, 64);
                part += __shfl_xor(part, 4, 64);
                part += __shfl_xor(part, 8, 64);
                if (l15 == 0 && row < M) atomicAdd(&e[row], part);
            }
        }
    }
}

// ---------------------------------------------------------------------------
// Final segment-sum: out[sid[a]] += (e[a] + comp_w[species[a]]) * 0.5
// ---------------------------------------------------------------------------
__global__ __launch_bounds__(256) void final_seg(
    const float* __restrict__ e, const float* __restrict__ comp_w,
    const int* __restrict__ species, const int* __restrict__ sid,
    float* __restrict__ out, int n_atoms)
{
    __shared__ float acc40[40];
    int t = threadIdx.x;
    if (t < 40) acc40[t] = 0.0f;
    __syncthreads();
    int a = blockIdx.x * 256 + t;
    if (a < n_atoms)
        atomicAdd(&acc40[sid[a]], (e[a] + comp_w[species[a]]) * 0.5f);
    __syncthreads();
    if (t < 40 && acc40[t] != 0.0f) atomicAdd(&out[t], acc40[t]);
}

// ---------------------------------------------------------------------------
extern "C" void kernel_launch(void* const* d_in, const int* in_sizes, int n_in,
                              void* d_out, int out_size, void* d_ws, size_t ws_size,
                              hipStream_t stream)
{
    const float* pos     = (const float*)d_in[0];
    const int*   pairs   = (const int*)d_in[1];
    const int*   species = (const int*)d_in[2];
    const int*   sid     = (const int*)d_in[3];
    const float* W_rad   = (const float*)d_in[4];
    const float* W_alch  = (const float*)d_in[5];
    const float* gamma   = (const float*)d_in[6];
    const float* beta    = (const float*)d_in[7];
    const float* W1      = (const float*)d_in[8];
    const float* W2      = (const float*)d_in[9];
    const float* W_last  = (const float*)d_in[10];
    const float* comp_w  = (const float*)d_in[11];

    int n_atoms = in_sizes[0] / 3;   // 4000
    int n_pairs = in_sizes[1] / 2;   // 160000
    float* out = (float*)d_out;

    char* ws = (char*)d_ws;
    int*   cnt    = (int*)(ws);
    int*   cursor = (int*)(ws + 16384);
    int*   off    = (int*)(ws + 32768);
    int*   idx    = (int*)(ws + 49152);
    size_t o1 = 49152 + 640 * 1024;                               // 704512
    unsigned short* W1symT = (unsigned short*)(ws + o1);          // 1024 x 2112 bf16
    size_t o2 = o1 + (size_t)1024 * 2112 * 2;                     // 5029888
    unsigned short* W2T = (unsigned short*)(ws + o2);             // 4 x 256 x 256 bf16
    size_t o3 = o2 + (size_t)4 * 256 * 256 * 2;                   // 5554176
    float* b1 = (float*)(ws + o3);                                // 1024 f32
    size_t o4 = o3 + 4096;                                        // 5558272
    unsigned short* Fu = (unsigned short*)(ws + o4);              // 4096 x 2112 bf16
    size_t o5 = o4 + (size_t)4096 * 2112 * 2;                     // 22859776
    unsigned short* H1 = (unsigned short*)(ws + o5);              // 4 x 4096 x 256 bf16
    size_t o6 = o5 + (size_t)4 * 4096 * 256 * 2;                  // 31248384
    float* e = (float*)(ws + o6);                                 // 4096 f32

    hipMemsetAsync(cnt, 0, 32768, stream);                        // cnt + cursor
    hipMemsetAsync(out, 0, (size_t)out_size * sizeof(float), stream);
    hipMemsetAsync(b1, 0, 4096, stream);
    hipMemsetAsync(e, 0, 4096 * sizeof(float), stream);
    hipMemsetAsync(Fu + (size_t)n_atoms * 2112, 0,
                   (size_t)(4096 - n_atoms) * 2112 * 2, stream);

    count_kernel<<<(n_pairs + 255) / 256, 256, 0, stream>>>(pairs, cnt, n_pairs);
    scan_kernel<<<1, 256, 0, stream>>>(cnt, off, n_atoms);
    fill_kernel<<<(n_pairs + 255) / 256, 256, 0, stream>>>(pairs, off, cursor, idx, n_pairs);

    prep_w1sym<<<dim3(33, 4), 256, 0, stream>>>(W1, gamma, beta, W1symT, b1);
    transpose_w<<<dim3(256 / 64, 256 / 64, 4), 256, 0, stream>>>(W2, W2T, 256, 256);

    gather_atom_kernel<<<n_atoms, 256, 0, stream>>>(
        pos, pairs, species, W_rad, W_alch, off, idx, Fu, n_atoms, n_pairs);

    // GEMM1: Fu [4096pad x 2112] @ W1symT [1024 x 2112]^T -> H1 (bf16)
    gemm_mfma<1><<<dim3(32, 16, 1), 256, 0, stream>>>(
        Fu, W1symT, H1, n_atoms, 2112, 0L, 0L, species, W_alch, W_last, b1);

    // GEMM2: H1[q] [4096pad x 256] @ W2T[q] [256 x 256]^T -> e (fused W_last)
    gemm_mfma<2><<<dim3(32, 4, 4), 256, 0, stream>>>(
        H1, W2T, e, n_atoms, 256, 4096L * 256, 256L * 256, species, W_alch, W_last, b1);

    final_seg<<<(n_atoms + 255) / 256, 256, 0, stream>>>(
        e, comp_w, species, sid, out, n_atoms);
}

// Round 8
// 149.178 us; speedup vs baseline: 1.1825x; 1.1825x over previous
//
#include <hip/hip_runtime.h>
#include <math.h>

typedef __attribute__((ext_vector_type(8))) short short8v;
typedef __attribute__((ext_vector_type(4))) float f32x4;

static constexpr float RCf = 5.0f;
static constexpr float PIf = 3.14159265358979323846f;

__device__ inline unsigned short f2bf(float f) {
    union { float f; unsigned u; } x; x.f = f;
    unsigned u = x.u;
    unsigned r = (u + 0x7fffu + ((u >> 16) & 1u)) >> 16;
    return (unsigned short)r;
}

// ---------------------------------------------------------------------------
// CSR build: count -> scan -> fill
// ---------------------------------------------------------------------------
__global__ __launch_bounds__(256) void count_kernel(
    const int* __restrict__ pairs, int* __restrict__ cnt, int n_pairs)
{
    int p = blockIdx.x * 256 + threadIdx.x;
    if (p < n_pairs) atomicAdd(&cnt[pairs[2 * p]], 1);
}

__global__ __launch_bounds__(256) void scan_kernel(
    const int* __restrict__ cnt, int* __restrict__ off, int n_atoms)
{
    __shared__ int part[256];
    int t = threadIdx.x;
    const int per = 16;
    int base = t * per;
    int local[16];
    int s = 0;
#pragma unroll
    for (int k = 0; k < per; k++) {
        int v = (base + k < n_atoms) ? cnt[base + k] : 0;
        local[k] = s;
        s += v;
    }
    part[t] = s;
    __syncthreads();
    for (int d = 1; d < 256; d <<= 1) {
        int v = (t >= d) ? part[t - d] : 0;
        __syncthreads();
        part[t] += v;
        __syncthreads();
    }
    int pre = (t == 0) ? 0 : part[t - 1];
#pragma unroll
    for (int k = 0; k < per; k++)
        if (base + k < n_atoms) off[base + k] = pre + local[k];
}

__global__ __launch_bounds__(256) void fill_kernel(
    const int* __restrict__ pairs, const int* __restrict__ off,
    int* __restrict__ cursor, int* __restrict__ idx, int n_pairs)
{
    int p = blockIdx.x * 256 + threadIdx.x;
    if (p >= n_pairs) return;
    int i = pairs[2 * p];
    int slot = atomicAdd(&cursor[i], 1);
    idx[off[i] + slot] = p;
}

// ---------------------------------------------------------------------------
// Transpose + bf16 cast: W [q][K][N] f32 -> WT [(q*N + n)][K] bf16  (for W2)
// ---------------------------------------------------------------------------
__global__ __launch_bounds__(256) void transpose_w(
    const float* __restrict__ W, unsigned short* __restrict__ WT, int K, int N)
{
    __shared__ float tile[64][65];
    int q = blockIdx.z;
    int k0 = blockIdx.x * 64, n0 = blockIdx.y * 64;
    const float* Wq = W + (size_t)q * K * N;
    int t = threadIdx.x;
    int kl = t >> 6, nl = t & 63;
#pragma unroll
    for (int i = 0; i < 16; i++)
        tile[kl + i * 4][nl] = Wq[(size_t)(k0 + kl + i * 4) * N + n0 + nl];
    __syncthreads();
    int nr = t >> 2, kc = (t & 3) * 16;
    unsigned short* dst = WT + ((size_t)q * N + n0 + nr) * K + k0 + kc;
    short8v v0, v1;
#pragma unroll
    for (int i = 0; i < 8; i++) {
        v0[i] = (short)f2bf(tile[kc + i][nr]);
        v1[i] = (short)f2bf(tile[kc + 8 + i][nr]);
    }
    *(short8v*)(dst) = v0;
    *(short8v*)(dst + 8) = v1;
}

// ---------------------------------------------------------------------------
// Symmetry-folded W1 prep (parallel version; round-7's serial 64-iter loop at
// 132 blocks was latency-bound: 60 µs, VALUBusy 1.6%, Occ 5%).
//   grid (132, 4): 16 u's per block, fully unrolled -> ~32 independent loads
//   in flight per thread; thread = h.
//   W1symT[(q*256+h)][u] = g[p1]*W1[q][p1][h] + (p1!=p2)*g[p2]*W1[q][p2][h]
//   b1[q][h]            = sum_pos beta[pos]*W1[q][pos][h]
// ---------------------------------------------------------------------------
__global__ __launch_bounds__(256) void prep_w1sym(
    const float* __restrict__ W1, const float* __restrict__ gamma,
    const float* __restrict__ beta, unsigned short* __restrict__ W1symT,
    float* __restrict__ b1)
{
    int u0 = blockIdx.x * 16;
    int q = blockIdx.y;
    int h = threadIdx.x;
    int l = u0 / 528, r = u0 % 528;
    int A = 0;
    while ((A + 1) * 32 - (A + 1) * A / 2 <= r) A++;     // rowstart(A+1) <= r
    int B = A + (r - (A * 32 - A * (A - 1) / 2));

    const float* W1q = W1 + (size_t)q * 4096 * 256;
    float bacc = 0.0f;
    short8v buf0, buf1;
#pragma unroll
    for (int uu = 0; uu < 16; uu++) {
        int pos1 = l * 1024 + (A >> 3) * 256 + (B >> 3) * 64 + (A & 7) * 8 + (B & 7);
        float w1 = W1q[(size_t)pos1 * 256 + h];
        float v = gamma[pos1] * w1;
        bacc += beta[pos1] * w1;
        if (A < B) {
            int pos2 = l * 1024 + (B >> 3) * 256 + (A >> 3) * 64 + (B & 7) * 8 + (A & 7);
            float w2 = W1q[(size_t)pos2 * 256 + h];
            v += gamma[pos2] * w2;
            bacc += beta[pos2] * w2;
        }
        unsigned short bv = f2bf(v);
        if (uu < 8) buf0[uu] = (short)bv; else buf1[uu - 8] = (short)bv;
        B++;
        if (B == 32) { A++; B = A; if (A == 32) { A = 0; B = 0; l++; } }
    }
    unsigned short* dst = W1symT + ((size_t)q * 256 + h) * 2112 + u0;
    *(short8v*)dst = buf0;
    *(short8v*)(dst + 8) = buf1;
    atomicAdd(&b1[q * 256 + h], bacc);
}

// ---------------------------------------------------------------------------
// Fused gather + power-spectrum + LayerNorm -> unique-position bf16 Fu.
// ---------------------------------------------------------------------------
__global__ __launch_bounds__(256) void gather_atom_kernel(
    const float* __restrict__ pos, const int* __restrict__ pairs,
    const int* __restrict__ species, const float* __restrict__ W_rad,
    const float* __restrict__ W_alch, const int* __restrict__ off,
    const int* __restrict__ idx, unsigned short* __restrict__ Fu,
    int n_atoms, int n_pairs)
{
    int atom = blockIdx.x;
    int t = threadIdx.x;
    __shared__ float wr2[512];        // W_rad transposed: [rr][n*4+l]
    __shared__ float raw_sh[16][16];
    __shared__ float Y_sh[16][16];
    __shared__ float wal_sh[16][4];
    __shared__ float R_sh[16][32];    // [pair][n*4+l]
    __shared__ float part[2][512];
    __shared__ float c_sh[512];
    __shared__ float red[8];

    for (int u = t; u < 512; u += 256) {
        int l = u >> 7, rr = (u >> 3) & 15, n = u & 7;
        wr2[rr * 32 + n * 4 + l] = W_rad[u];
    }

    int p0 = off[atom];
    int p1 = (atom + 1 < n_atoms) ? off[atom + 1] : n_pairs;
    int npair = p1 - p0;

    float px = pos[3 * atom], py = pos[3 * atom + 1], pz = pos[3 * atom + 2];

    int half = t >> 7, e = t & 127;
    int lm = e >> 3, nn = e & 7;
    int l_of = (lm > 0) + (lm > 3) + (lm > 8);
    int nl_of = nn * 4 + l_of;
    float acc0 = 0.f, acc1 = 0.f, acc2 = 0.f, acc3 = 0.f;

    __syncthreads();

    for (int done = 0; done < npair; done += 16) {
        int pp = t >> 4, sub = t & 15;
        // ---- A1: geometry + raw + Y + walch for 16 pairs ----
        {
            int k = done + pp;
            float xx = 0.f, yy = 0.f, zz = 0.f;
            int sj = 0;
            if (k < npair) {
                int pid = idx[p0 + k];
                int j = pairs[2 * pid + 1];
                sj = species[j];
                float dx = pos[3 * j]     - px;
                float dy = pos[3 * j + 1] - py;
                float dz = pos[3 * j + 2] - pz;
                float r = sqrtf(dx * dx + dy * dy + dz * dz + 1e-12f);
                float inv = 1.0f / r;
                xx = dx * inv; yy = dy * inv; zz = dz * inv;
                float fc = (r < RCf) ? 0.5f * (cosf((PIf / RCf) * r) + 1.0f) : 0.0f;
                float mu = (RCf / 15.0f) * (float)sub;
                float tt = (r - mu) * (16.0f / RCf);
                raw_sh[pp][sub] = expf(-tt * tt) * fc;
            } else {
                raw_sh[pp][sub] = 0.0f;
            }
            float x2 = xx * xx, y2 = yy * yy, z2 = zz * zz;
            float yv;
            switch (sub) {
                case 0:  yv = 0.28209479177387814f; break;
                case 1:  yv = 0.4886025119029199f * yy; break;
                case 2:  yv = 0.4886025119029199f * zz; break;
                case 3:  yv = 0.4886025119029199f * xx; break;
                case 4:  yv = 1.0925484305920792f * xx * yy; break;
                case 5:  yv = 1.0925484305920792f * yy * zz; break;
                case 6:  yv = 0.31539156525252005f * (3.0f * z2 - 1.0f); break;
                case 7:  yv = 1.0925484305920792f * xx * zz; break;
                case 8:  yv = 0.5462742152960396f * (x2 - y2); break;
                case 9:  yv = 0.5900435899266435f * yy * (3.0f * x2 - y2); break;
                case 10: yv = 2.890611442640554f * xx * yy * zz; break;
                case 11: yv = 0.4570457994644658f * yy * (5.0f * z2 - 1.0f); break;
                case 12: yv = 0.3731763325901154f * zz * (5.0f * z2 - 3.0f); break;
                case 13: yv = 0.4570457994644658f * xx * (5.0f * z2 - 1.0f); break;
                case 14: yv = 1.445305721320277f * zz * (x2 - y2); break;
                default: yv = 0.5900435899266435f * xx * (x2 - 3.0f * y2); break;
            }
            Y_sh[pp][sub] = yv;
            if (sub < 4) wal_sh[pp][sub] = W_alch[sj * 4 + sub];
        }
        __syncthreads();
        // ---- A1.5: R_sh[pp][n*4+l] ----
#pragma unroll
        for (int rep = 0; rep < 2; rep++) {
            int id = rep * 256 + t;
            int pp2 = id >> 5, nl = id & 31;
            float acc = 0.f;
            const float* rw = raw_sh[pp2];
            const float* wv = &wr2[nl];
#pragma unroll
            for (int rr = 0; rr < 16; rr++)
                acc = fmaf(rw[rr], wv[rr * 32], acc);
            R_sh[pp2][nl] = acc;
        }
        __syncthreads();
        // ---- A2: accumulate 8 pairs per half ----
        int base = half * 8;
#pragma unroll
        for (int pq = 0; pq < 8; pq++) {
            int pp2 = base + pq;
            float contrib = Y_sh[pp2][lm] * R_sh[pp2][nl_of];
            const float* wa = wal_sh[pp2];
            acc0 = fmaf(wa[0], contrib, acc0);
            acc1 = fmaf(wa[1], contrib, acc1);
            acc2 = fmaf(wa[2], contrib, acc2);
            acc3 = fmaf(wa[3], contrib, acc3);
        }
        __syncthreads();
    }

    part[half][0 * 128 + e] = acc0;
    part[half][1 * 128 + e] = acc1;
    part[half][2 * 128 + e] = acc2;
    part[half][3 * 128 + e] = acc3;
    __syncthreads();
    c_sh[t]       = part[0][t]       + part[1][t];
    c_sh[t + 256] = part[0][t + 256] + part[1][t + 256];
    __syncthreads();

    const float invsq[4] = {1.0f, 0.57735026918962576f, 0.44721359549995794f,
                            0.37796447300922722f};
    int b = t >> 6, n = (t >> 3) & 7, k = t & 7;
    float fv[16];
    float lsum = 0.0f;
#pragma unroll
    for (int ii = 0; ii < 16; ii++) {
        int l = ii >> 2, a = ii & 3;
        int base = l * l;
        float acc = 0.0f;
        int cntm = 2 * l + 1;
        for (int m = 0; m < cntm; m++)
            acc = fmaf(c_sh[a * 128 + (base + m) * 8 + n],
                       c_sh[b * 128 + (base + m) * 8 + k], acc);
        acc *= invsq[l];
        fv[ii] = acc;
        lsum += acc;
    }

    float v = lsum;
#pragma unroll
    for (int o = 1; o < 64; o <<= 1) v += __shfl_xor(v, o, 64);
    int wid = t >> 6, lane = t & 63;
    if (lane == 0) red[wid] = v;
    __syncthreads();
    float mean = (red[0] + red[1] + red[2] + red[3]) * (1.0f / 4096.0f);

    float lss = 0.0f;
#pragma unroll
    for (int ii = 0; ii < 16; ii++) {
        float d = fv[ii] - mean;
        lss += d * d;
    }
    v = lss;
#pragma unroll
    for (int o = 1; o < 64; o <<= 1) v += __shfl_xor(v, o, 64);
    if (lane == 0) red[4 + wid] = v;
    __syncthreads();
    float var = (red[4] + red[5] + red[6] + red[7]) * (1.0f / 4096.0f);
    float rs = rsqrtf(var + 1e-5f);

    // write only unique positions A<=B:  u = l*528 + 32A - A(A+1)/2 + B
    unsigned short* Fo = Fu + (size_t)atom * 2112;
    int B = b * 8 + k;
#pragma unroll
    for (int ii = 0; ii < 16; ii++) {
        int l = ii >> 2, a = ii & 3;
        int A = a * 8 + n;
        if (A <= B) {
            int u = l * 528 + A * 32 - (A * (A + 1)) / 2 + B;
            Fo[u] = f2bf((fv[ii] - mean) * rs);
        }
    }
}

// ---------------------------------------------------------------------------
// bf16 MFMA GEMM, SINGLE-buffer (24 KB LDS). Measured: single-buffer 66-69 µs
// vs dbuf-48KB 81 µs (occupancy loss beats overlap — keep single).
// NO XCD swizzle (round-4: tripled FETCH). BM=128, BN=64, BK=64;
// chunk-XOR LDS swizzle (rule #21).
//   MODE 1: A=Fu K=2112; v=(acc+b1[q,h])*alch; silu -> bf16 H1 (all rows).
//   MODE 2: per-q K=256; fused W_last dot -> atomicAdd e[row].
// ---------------------------------------------------------------------------
template<int MODE>
__global__ __launch_bounds__(256) void gemm_mfma(
    const unsigned short* __restrict__ A, const unsigned short* __restrict__ B,
    void* __restrict__ C, int M, int K, long sAq, long sBq,
    const int* __restrict__ species, const float* __restrict__ W_alch,
    const float* __restrict__ W_last, const float* __restrict__ b1)
{
    __shared__ unsigned short As[128 * 64];  // 16 KB
    __shared__ unsigned short Bs[64 * 64];   // 8 KB
    int t = threadIdx.x, w = t >> 6, lane = t & 63;
    int bm = blockIdx.x * 128, bn = blockIdx.y * 64;
    int q = blockIdx.z;

    const unsigned short* Aq = A + (size_t)q * sAq;
    const unsigned short* Bq = B + (size_t)q * sBq;
    int ldab = K * 2;

    long srcoff = (long)(lane >> 3) * ldab + (long)(((lane & 7) ^ (lane >> 3)) << 4);
    const char* Ab = (const char*)Aq + (size_t)bm * ldab + srcoff;
    const char* Bb = (const char*)Bq + (size_t)bn * ldab + srcoff;

    int wr = w >> 1, wc = w & 1;
    f32x4 acc[4][2];
#pragma unroll
    for (int i = 0; i < 4; i++)
#pragma unroll
        for (int j = 0; j < 2; j++) acc[i][j] = (f32x4){0.f, 0.f, 0.f, 0.f};

    int l15 = lane & 15, l16 = lane >> 4;
    int rA0 = wr * 64 + l15;
    int rB0 = wc * 32 + l15;
    int cb0 = l16 * 16;
    int swzA = (rA0 & 7) << 4, swzB = (rB0 & 7) << 4;

    for (int k0 = 0; k0 < K; k0 += 64) {
        long kb = (long)k0 * 2;
#pragma unroll
        for (int i = 0; i < 4; i++) {
            int c = w * 4 + i;
            __builtin_amdgcn_global_load_lds(
                (const __attribute__((address_space(1))) unsigned int*)(Ab + (size_t)(c * 8) * ldab + kb),
                (__attribute__((address_space(3))) unsigned int*)(As + c * 512), 16, 0, 0);
        }
#pragma unroll
        for (int i = 0; i < 2; i++) {
            int c = w * 2 + i;
            __builtin_amdgcn_global_load_lds(
                (const __attribute__((address_space(1))) unsigned int*)(Bb + (size_t)(c * 8) * ldab + kb),
                (__attribute__((address_space(3))) unsigned int*)(Bs + c * 512), 16, 0, 0);
        }
        __syncthreads();

        short8v a[4][2], bfr[2][2];
#pragma unroll
        for (int mb = 0; mb < 4; mb++)
#pragma unroll
            for (int kk = 0; kk < 2; kk++) {
                int addr = (rA0 + mb * 16) * 128 + ((cb0 + kk * 64) ^ swzA);
                a[mb][kk] = *(const short8v*)((const char*)As + addr);
            }
#pragma unroll
        for (int nb = 0; nb < 2; nb++)
#pragma unroll
            for (int kk = 0; kk < 2; kk++) {
                int addr = (rB0 + nb * 16) * 128 + ((cb0 + kk * 64) ^ swzB);
                bfr[nb][kk] = *(const short8v*)((const char*)Bs + addr);
            }
#pragma unroll
        for (int kk = 0; kk < 2; kk++)
#pragma unroll
            for (int mb = 0; mb < 4; mb++)
#pragma unroll
                for (int nb = 0; nb < 2; nb++)
                    acc[mb][nb] = __builtin_amdgcn_mfma_f32_16x16x32_bf16(
                        a[mb][kk], bfr[nb][kk], acc[mb][nb], 0, 0, 0);
        __syncthreads();
    }

    int colbase = bn + wc * 32 + l15;
    if (MODE == 1) {
#pragma unroll
        for (int mb = 0; mb < 4; mb++) {
#pragma unroll
            for (int j = 0; j < 4; j++) {
                int row = bm + wr * 64 + mb * 16 + l16 * 4 + j;
                int sp = species[row < M ? row : (M - 1)];
#pragma unroll
                for (int nb = 0; nb < 2; nb++) {
                    int gcol = colbase + nb * 16;
                    int qq = gcol >> 8, hc = gcol & 255;
                    float v = (acc[mb][nb][j] + b1[gcol]) * W_alch[sp * 4 + qq];
                    v = v / (1.0f + expf(-v));
                    ((unsigned short*)C)[((size_t)qq * 4096 + row) * 256 + hc] = f2bf(v);
                }
            }
        }
    } else {
        float wl0 = W_last[q * 256 + colbase];
        float wl1 = W_last[q * 256 + colbase + 16];
        float* e = (float*)C;
#pragma unroll
        for (int mb = 0; mb < 4; mb++) {
#pragma unroll
            for (int j = 0; j < 4; j++) {
                int row = bm + wr * 64 + mb * 16 + l16 * 4 + j;
                float v0 = acc[mb][0][j]; v0 = v0 / (1.0f + expf(-v0));
                float v1 = acc[mb][1][j]; v1 = v1 / (1.0f + expf(-v1));
                float part = v0 * wl0 + v1 * wl1;
                part += __shfl_xor(part, 1, 64);
                part += __shfl_xor(part, 2, 64);
                part += __shfl_xor(part, 4, 64);
                part += __shfl_xor(part, 8, 64);
                if (l15 == 0 && row < M) atomicAdd(&e[row], part);
            }
        }
    }
}

// ---------------------------------------------------------------------------
// Final segment-sum: out[sid[a]] += (e[a] + comp_w[species[a]]) * 0.5
// ---------------------------------------------------------------------------
__global__ __launch_bounds__(256) void final_seg(
    const float* __restrict__ e, const float* __restrict__ comp_w,
    const int* __restrict__ species, const int* __restrict__ sid,
    float* __restrict__ out, int n_atoms)
{
    __shared__ float acc40[40];
    int t = threadIdx.x;
    if (t < 40) acc40[t] = 0.0f;
    __syncthreads();
    int a = blockIdx.x * 256 + t;
    if (a < n_atoms)
        atomicAdd(&acc40[sid[a]], (e[a] + comp_w[species[a]]) * 0.5f);
    __syncthreads();
    if (t < 40 && acc40[t] != 0.0f) atomicAdd(&out[t], acc40[t]);
}

// ---------------------------------------------------------------------------
extern "C" void kernel_launch(void* const* d_in, const int* in_sizes, int n_in,
                              void* d_out, int out_size, void* d_ws, size_t ws_size,
                              hipStream_t stream)
{
    const float* pos     = (const float*)d_in[0];
    const int*   pairs   = (const int*)d_in[1];
    const int*   species = (const int*)d_in[2];
    const int*   sid     = (const int*)d_in[3];
    const float* W_rad   = (const float*)d_in[4];
    const float* W_alch  = (const float*)d_in[5];
    const float* gamma   = (const float*)d_in[6];
    const float* beta    = (const float*)d_in[7];
    const float* W1      = (const float*)d_in[8];
    const float* W2      = (const float*)d_in[9];
    const float* W_last  = (const float*)d_in[10];
    const float* comp_w  = (const float*)d_in[11];

    int n_atoms = in_sizes[0] / 3;   // 4000
    int n_pairs = in_sizes[1] / 2;   // 160000
    float* out = (float*)d_out;

    char* ws = (char*)d_ws;
    int*   cnt    = (int*)(ws);
    int*   cursor = (int*)(ws + 16384);
    int*   off    = (int*)(ws + 32768);
    int*   idx    = (int*)(ws + 49152);
    size_t o1 = 49152 + 640 * 1024;                               // 704512
    unsigned short* W1symT = (unsigned short*)(ws + o1);          // 1024 x 2112 bf16
    size_t o2 = o1 + (size_t)1024 * 2112 * 2;                     // 5029888
    unsigned short* W2T = (unsigned short*)(ws + o2);             // 4 x 256 x 256 bf16
    size_t o3 = o2 + (size_t)4 * 256 * 256 * 2;                   // 5554176
    float* b1 = (float*)(ws + o3);                                // 1024 f32
    size_t o4 = o3 + 4096;                                        // 5558272
    unsigned short* Fu = (unsigned short*)(ws + o4);              // 4096 x 2112 bf16
    size_t o5 = o4 + (size_t)4096 * 2112 * 2;                     // 22859776
    unsigned short* H1 = (unsigned short*)(ws + o5);              // 4 x 4096 x 256 bf16
    size_t o6 = o5 + (size_t)4 * 4096 * 256 * 2;                  // 31248384
    float* e = (float*)(ws + o6);                                 // 4096 f32

    hipMemsetAsync(cnt, 0, 32768, stream);                        // cnt + cursor
    hipMemsetAsync(out, 0, (size_t)out_size * sizeof(float), stream);
    hipMemsetAsync(b1, 0, 4096, stream);
    hipMemsetAsync(e, 0, 4096 * sizeof(float), stream);
    hipMemsetAsync(Fu + (size_t)n_atoms * 2112, 0,
                   (size_t)(4096 - n_atoms) * 2112 * 2, stream);

    count_kernel<<<(n_pairs + 255) / 256, 256, 0, stream>>>(pairs, cnt, n_pairs);
    scan_kernel<<<1, 256, 0, stream>>>(cnt, off, n_atoms);
    fill_kernel<<<(n_pairs + 255) / 256, 256, 0, stream>>>(pairs, off, cursor, idx, n_pairs);

    prep_w1sym<<<dim3(132, 4), 256, 0, stream>>>(W1, gamma, beta, W1symT, b1);
    transpose_w<<<dim3(256 / 64, 256 / 64, 4), 256, 0, stream>>>(W2, W2T, 256, 256);

    gather_atom_kernel<<<n_atoms, 256, 0, stream>>>(
        pos, pairs, species, W_rad, W_alch, off, idx, Fu, n_atoms, n_pairs);

    // GEMM1: Fu [4096pad x 2112] @ W1symT [1024 x 2112]^T -> H1 (bf16)
    gemm_mfma<1><<<dim3(32, 16, 1), 256, 0, stream>>>(
        Fu, W1symT, H1, n_atoms, 2112, 0L, 0L, species, W_alch, W_last, b1);

    // GEMM2: H1[q] [4096pad x 256] @ W2T[q] [256 x 256]^T -> e (fused W_last)
    gemm_mfma<2><<<dim3(32, 4, 4), 256, 0, stream>>>(
        H1, W2T, e, n_atoms, 256, 4096L * 256, 256L * 256, species, W_alch, W_last, b1);

    final_seg<<<(n_atoms + 255) / 256, 256, 0, stream>>>(
        e, comp_w, species, sid, out, n_atoms);
}